// Round 4
// baseline (191881.262 us; speedup 1.0000x reference)
//
#include <hip/hip_runtime.h>
#include <hip/hip_bf16.h>
#include <stdint.h>

constexpr int kSEQ = 8192;
constexpr int kIN  = 1024;
constexpr int kH   = 2048;
constexpr int kG4  = 4 * kH;   // 8192 gate rows
constexpr int kNB  = 256;      // persistent workgroups (1 per CU)
constexpr int kHB  = kH / kNB; // 8 h-values owned per WG

// ---- workspace layout (bytes) ----
constexpr size_t OFF_HG    = 0;          // float h[2][kH]      (16 KB, double-buffered)
constexpr size_t OFF_FLAGS = 16384;      // uint32 flags[kNB]   (1 KB)
constexpr size_t OFF_ABORT = 17408;      // uint32 abort flag
constexpr size_t OFF_HS    = 65536;      // bf16 hs[kSEQ][kH]   (32 MB)
constexpr size_t OFF_XP    = OFF_HS + (size_t)kSEQ * kH * 2; // bf16 xp[kSEQ][kG4] (128 MB)

__device__ __forceinline__ float bflo(uint32_t v) { return __uint_as_float(v << 16); }
__device__ __forceinline__ float bfhi(uint32_t v) { return __uint_as_float(v & 0xffff0000u); }

// ---------------------------------------------------------------------------
// Kernel 1: x_proj[m][n] = sum_k input[m][k] * W_ih[n][k] + b_ih[n] + b_hh[n]
// fp32 LDS-tiled GEMM, 64x64 tile, BK=16, 256 threads, 4x4 per thread.
// ---------------------------------------------------------------------------
__global__ __launch_bounds__(256) void k_xproj(const float* __restrict__ A,
                                               const float* __restrict__ B,
                                               const float* __restrict__ bih,
                                               const float* __restrict__ bhh,
                                               __hip_bfloat16* __restrict__ C)
{
    __shared__ float As[16][65];
    __shared__ float Bs[16][65];

    const int bx = blockIdx.x & 127;   // n tile
    const int by = blockIdx.x >> 7;    // m tile
    const int tid = threadIdx.x;
    const int r  = tid >> 2;           // 0..63 row within tile
    const int kq = (tid & 3) << 2;     // 0,4,8,12
    const int tx = tid & 15;
    const int ty = tid >> 4;
    const int m0 = by * 64, n0 = bx * 64;

    float acc[4][4] = {};

    for (int k0 = 0; k0 < kIN; k0 += 16) {
        float4 av = *(const float4*)&A[(size_t)(m0 + r) * kIN + k0 + kq];
        float4 bv = *(const float4*)&B[(size_t)(n0 + r) * kIN + k0 + kq];
        __syncthreads();   // protect previous iteration's reads
        As[kq + 0][r] = av.x; As[kq + 1][r] = av.y; As[kq + 2][r] = av.z; As[kq + 3][r] = av.w;
        Bs[kq + 0][r] = bv.x; Bs[kq + 1][r] = bv.y; Bs[kq + 2][r] = bv.z; Bs[kq + 3][r] = bv.w;
        __syncthreads();
        #pragma unroll
        for (int k = 0; k < 16; ++k) {
            float a0 = As[k][ty * 4 + 0], a1 = As[k][ty * 4 + 1];
            float a2 = As[k][ty * 4 + 2], a3 = As[k][ty * 4 + 3];
            float b0 = Bs[k][tx * 4 + 0], b1 = Bs[k][tx * 4 + 1];
            float b2 = Bs[k][tx * 4 + 2], b3 = Bs[k][tx * 4 + 3];
            acc[0][0] += a0 * b0; acc[0][1] += a0 * b1; acc[0][2] += a0 * b2; acc[0][3] += a0 * b3;
            acc[1][0] += a1 * b0; acc[1][1] += a1 * b1; acc[1][2] += a1 * b2; acc[1][3] += a1 * b3;
            acc[2][0] += a2 * b0; acc[2][1] += a2 * b1; acc[2][2] += a2 * b2; acc[2][3] += a2 * b3;
            acc[3][0] += a3 * b0; acc[3][1] += a3 * b1; acc[3][2] += a3 * b2; acc[3][3] += a3 * b3;
        }
    }

    #pragma unroll
    for (int i = 0; i < 4; ++i) {
        const int m = m0 + ty * 4 + i;
        #pragma unroll
        for (int j = 0; j < 4; ++j) {
            const int n = n0 + tx * 4 + j;
            C[(size_t)m * kG4 + n] = __float2bfloat16(acc[i][j] + bih[n] + bhh[n]);
        }
    }
}

// ---------------------------------------------------------------------------
// Kernel 2: persistent LSTM recurrence. 256 WGs x 256 threads, 1 WG/CU.
// WG wg owns h indices [wg*8, wg*8+8) => 32 gate rows (8 per gate).
// Wave w (0..3) computes gate w. W_hh slice lives in LDS as bf16.
// Launched COOPERATIVELY (driver guarantees co-residency -> flag barrier is
// live). Fallback plain launch uses a WHOLE-KERNEL poll budget + sticky
// device-scope abort: absolute worst case ~1.5 s then uniform grid exit.
// ---------------------------------------------------------------------------
__global__ __launch_bounds__(256, 1) void k_lstm(const float* __restrict__ Whh,
                                                 const __hip_bfloat16* __restrict__ xp,
                                                 float* __restrict__ hg,        // [2][kH]
                                                 uint32_t* __restrict__ flags,  // [kNB]
                                                 uint32_t* __restrict__ abortf,
                                                 __hip_bfloat16* __restrict__ hs)
{
    extern __shared__ char smem[];
    __hip_bfloat16* Wl   = (__hip_bfloat16*)smem;                     // [32][kH] bf16
    float*          hl   = (float*)(smem + 32 * kH * 2);              // [kH] fp32
    float*          gbuf = (float*)(smem + 32 * kH * 2 + kH * 4);     // [4][8]
    float*          xbuf = gbuf + 32;                                 // [4][8]

    const int wg  = blockIdx.x;
    const int tid = threadIdx.x;
    const int w   = tid >> 6;   // wave id == gate id
    const int l   = tid & 63;
    const int hb  = wg * kHB;

    // ---- one-time: load + convert W_hh slice to LDS bf16 ----
    {
        const int lr = tid >> 3;             // LDS row 0..31
        const int g  = lr >> 3, j = lr & 7;  // gate, sub-index
        const int cb = (tid & 7) * 256;
        const float* src = Whh + (size_t)(g * kH + hb + j) * kH + cb;
        __hip_bfloat16* dst = Wl + lr * kH + cb;
        for (int c = 0; c < 256; c += 4) {
            float4 v = *(const float4*)(src + c);
            dst[c + 0] = __float2bfloat16(v.x);
            dst[c + 1] = __float2bfloat16(v.y);
            dst[c + 2] = __float2bfloat16(v.z);
            dst[c + 3] = __float2bfloat16(v.w);
        }
    }
    __syncthreads();

    float c_state = 0.0f;                                  // lanes tid<8 carry c
    const __hip_bfloat16* wrow = Wl + (w * 8 + (l >> 3)) * kH;
    const int kbase = (l & 7) * 8;
    uint32_t budget = 0;        // whole-kernel poll budget (liveness bound)

    for (int t = 0; t < kSEQ; ++t) {
        // ---- barrier: wait until every WG published h_{t-1} (flag >= t) ----
        {
            int dead = 0;
            while (__hip_atomic_load(&flags[tid], __ATOMIC_ACQUIRE,
                                     __HIP_MEMORY_SCOPE_AGENT) < (uint32_t)t) {
                if ((++budget & 1023) == 0) {
                    if (__hip_atomic_load(abortf, __ATOMIC_RELAXED,
                                          __HIP_MEMORY_SCOPE_AGENT) != 0u) { dead = 1; break; }
                    if (budget > (1u << 24)) {   // ~1.4 s total -> poison abort
                        __hip_atomic_store(abortf, 1u, __ATOMIC_RELAXED,
                                           __HIP_MEMORY_SCOPE_AGENT);
                        dead = 1; break;
                    }
                }
            }
            if (__syncthreads_or(dead)) return;   // uniform exit: never hang
        }

        // ---- stage h_{t-1} (buffer t&1) into LDS; fetch this step's x_proj ----
        // Plain vectorized loads are safe: the ACQUIRE spin above + __syncthreads
        // establishes happens-before with every producer's RELEASE flag store.
        {
            const float* src = hg + (size_t)(t & 1) * kH + tid * 8;
            float4 a = *(const float4*)(src);
            float4 b = *(const float4*)(src + 4);
            float* d = hl + tid * 8;
            *(float4*)(d)     = a;
            *(float4*)(d + 4) = b;
            if (tid < 32)
                xbuf[tid] = __bfloat162float(xp[(size_t)t * kG4 + (tid >> 3) * kH + hb + (tid & 7)]);
        }
        __syncthreads();

        // ---- matvec: lane (j=l>>3, ksub=l&7); 32 iters x 8 MACs ----
        float acc = 0.f;
        #pragma unroll 8
        for (int it = 0; it < 32; ++it) {
            const int k = it * 64 + kbase;
            uint4 wv = *(const uint4*)(wrow + k);
            float4 h0 = *(const float4*)(hl + k);
            float4 h1 = *(const float4*)(hl + k + 4);
            acc += bflo(wv.x) * h0.x + bfhi(wv.x) * h0.y
                 + bflo(wv.y) * h0.z + bfhi(wv.y) * h0.w
                 + bflo(wv.z) * h1.x + bfhi(wv.z) * h1.y
                 + bflo(wv.w) * h1.z + bfhi(wv.w) * h1.w;
        }
        acc += __shfl_xor(acc, 1);
        acc += __shfl_xor(acc, 2);
        acc += __shfl_xor(acc, 4);
        if ((l & 7) == 0) gbuf[w * 8 + (l >> 3)] = acc;
        __syncthreads();

        // ---- gate nonlinearities + state update (8 lanes) ----
        if (tid < 8) {
            const int j = tid;
            const float gi = gbuf[0 * 8 + j] + xbuf[0 * 8 + j];
            const float gf = gbuf[1 * 8 + j] + xbuf[1 * 8 + j];
            const float gg = gbuf[2 * 8 + j] + xbuf[2 * 8 + j];
            const float go = gbuf[3 * 8 + j] + xbuf[3 * 8 + j];
            const float si = 1.f / (1.f + expf(-gi));
            const float sf = 1.f / (1.f + expf(-gf));
            const float tg = tanhf(gg);
            const float so = 1.f / (1.f + expf(-go));
            c_state = sf * c_state + si * tg;
            const float hv = so * tanhf(c_state);
            hg[(size_t)((t + 1) & 1) * kH + hb + j] = hv;          // plain store
            hs[(size_t)t * kH + hb + j] = __float2bfloat16(hv);
        }
        __syncthreads();   // drains vmcnt for all waves before publish
        if (tid == 0)
            __hip_atomic_store(&flags[wg], (uint32_t)(t + 1), __ATOMIC_RELEASE,
                               __HIP_MEMORY_SCOPE_AGENT);
    }
}

// ---------------------------------------------------------------------------
// Kernel 3: out[t] = sigmoid(hs[t] . W_lin + b_lin). One wave per t.
// ---------------------------------------------------------------------------
__global__ __launch_bounds__(256) void k_out(const __hip_bfloat16* __restrict__ hs,
                                             const float* __restrict__ wlin,
                                             const float* __restrict__ blin,
                                             float* __restrict__ out)
{
    const int w = threadIdx.x >> 6, l = threadIdx.x & 63;
    const int t = blockIdx.x * 4 + w;
    const __hip_bfloat16* row = hs + (size_t)t * kH;
    float acc = 0.f;
    #pragma unroll
    for (int i = 0; i < 4; ++i) {
        const int k = i * 512 + l * 8;
        uint4 hv = *(const uint4*)(row + k);
        float4 w0 = *(const float4*)(wlin + k);
        float4 w1 = *(const float4*)(wlin + k + 4);
        acc += bflo(hv.x) * w0.x + bfhi(hv.x) * w0.y
             + bflo(hv.y) * w0.z + bfhi(hv.y) * w0.w
             + bflo(hv.z) * w1.x + bfhi(hv.z) * w1.y
             + bflo(hv.w) * w1.z + bfhi(hv.w) * w1.w;
    }
    #pragma unroll
    for (int s = 32; s >= 1; s >>= 1) acc += __shfl_xor(acc, s);
    if (l == 0) out[t] = 1.f / (1.f + expf(-(acc + blin[0])));
}

// ---------------------------------------------------------------------------
extern "C" void kernel_launch(void* const* d_in, const int* in_sizes, int n_in,
                              void* d_out, int out_size, void* d_ws, size_t ws_size,
                              hipStream_t stream)
{
    const float* input_seq = (const float*)d_in[0];
    const float* W_ih      = (const float*)d_in[1];
    const float* W_hh      = (const float*)d_in[2];
    const float* b_ih      = (const float*)d_in[3];
    const float* b_hh      = (const float*)d_in[4];
    const float* W_lin     = (const float*)d_in[5];
    const float* b_lin     = (const float*)d_in[6];
    float* out = (float*)d_out;
    char*  ws  = (char*)d_ws;

    float*          hg    = (float*)(ws + OFF_HG);
    uint32_t*       flags = (uint32_t*)(ws + OFF_FLAGS);
    uint32_t*       abf   = (uint32_t*)(ws + OFF_ABORT);
    __hip_bfloat16* hs    = (__hip_bfloat16*)(ws + OFF_HS);
    __hip_bfloat16* xpb   = (__hip_bfloat16*)(ws + OFF_XP);

    // zero h double-buffer + flags + abort each call (harness does not re-poison)
    hipMemsetAsync(ws, 0, 65536, stream);

    k_xproj<<<dim3(128 * 128), dim3(256), 0, stream>>>(input_seq, W_ih, b_ih, b_hh, xpb);

    constexpr int kLds = 32 * kH * 2 + kH * 4 + 64 * 4;   // 139520 B
    hipFuncSetAttribute((const void*)k_lstm, hipFuncAttributeMaxDynamicSharedMemorySize, kLds);

    // Preferred: cooperative launch -> driver guarantees all 256 WGs co-resident,
    // so the flag barrier is provably live. Fallback: plain launch (whole-kernel
    // bounded spin + sticky abort still prevents any hang).
    {
        const float* a0 = W_hh; const __hip_bfloat16* a1 = xpb; float* a2 = hg;
        uint32_t* a3 = flags; uint32_t* a4 = abf; __hip_bfloat16* a5 = hs;
        void* args[6] = { &a0, &a1, &a2, &a3, &a4, &a5 };
        hipError_t ce = hipLaunchCooperativeKernel((const void*)k_lstm, dim3(kNB), dim3(256),
                                                   args, (unsigned)kLds, stream);
        if (ce != hipSuccess) {
            k_lstm<<<dim3(kNB), dim3(256), kLds, stream>>>(W_hh, xpb, hg, flags, abf, hs);
        }
    }

    k_out<<<dim3(kSEQ / 4), dim3(256), 0, stream>>>(hs, W_lin, b_lin, out);
}

// Round 8
// 101162.762 us; speedup vs baseline: 1.8968x; 1.8968x over previous
//
#include <hip/hip_runtime.h>
#include <hip/hip_bf16.h>
#include <stdint.h>

constexpr int kSEQ = 8192;
constexpr int kIN  = 1024;
constexpr int kH   = 2048;
constexpr int kG4  = 4 * kH;   // 8192 gate rows
constexpr int kNB  = 256;      // persistent workgroups (1 per CU)
constexpr int kHB  = kH / kNB; // 8 h-values owned per WG
constexpr int kWP  = kH + 16;  // padded LDS row stride (breaks 8-way bank conflict)

// ---- workspace layout (bytes) ----
constexpr size_t OFF_HG    = 0;          // float h[2][kH]      (16 KB, double-buffered)
constexpr size_t OFF_FLAGS = 16384;      // uint32 flags[kNB]   (1 KB)
constexpr size_t OFF_ABORT = 17408;      // uint32 abort flag
constexpr size_t OFF_HS    = 65536;      // bf16 hs[kSEQ][kH]   (32 MB)
constexpr size_t OFF_XP    = OFF_HS + (size_t)kSEQ * kH * 2; // bf16 xp[kSEQ][kG4] (128 MB)

__device__ __forceinline__ float bflo(uint32_t v) { return __uint_as_float(v << 16); }
__device__ __forceinline__ float bfhi(uint32_t v) { return __uint_as_float(v & 0xffff0000u); }

// ---------------------------------------------------------------------------
// Kernel 1: x_proj[m][n] = sum_k input[m][k] * W_ih[n][k] + b_ih[n] + b_hh[n]
// fp32 LDS-tiled GEMM, 64x64 tile, BK=16, 256 threads, 4x4 per thread.
// ---------------------------------------------------------------------------
__global__ __launch_bounds__(256) void k_xproj(const float* __restrict__ A,
                                               const float* __restrict__ B,
                                               const float* __restrict__ bih,
                                               const float* __restrict__ bhh,
                                               __hip_bfloat16* __restrict__ C)
{
    __shared__ float As[16][65];
    __shared__ float Bs[16][65];

    const int bx = blockIdx.x & 127;   // n tile
    const int by = blockIdx.x >> 7;    // m tile
    const int tid = threadIdx.x;
    const int r  = tid >> 2;           // 0..63 row within tile
    const int kq = (tid & 3) << 2;     // 0,4,8,12
    const int tx = tid & 15;
    const int ty = tid >> 4;
    const int m0 = by * 64, n0 = bx * 64;

    float acc[4][4] = {};

    for (int k0 = 0; k0 < kIN; k0 += 16) {
        float4 av = *(const float4*)&A[(size_t)(m0 + r) * kIN + k0 + kq];
        float4 bv = *(const float4*)&B[(size_t)(n0 + r) * kIN + k0 + kq];
        __syncthreads();   // protect previous iteration's reads
        As[kq + 0][r] = av.x; As[kq + 1][r] = av.y; As[kq + 2][r] = av.z; As[kq + 3][r] = av.w;
        Bs[kq + 0][r] = bv.x; Bs[kq + 1][r] = bv.y; Bs[kq + 2][r] = bv.z; Bs[kq + 3][r] = bv.w;
        __syncthreads();
        #pragma unroll
        for (int k = 0; k < 16; ++k) {
            float a0 = As[k][ty * 4 + 0], a1 = As[k][ty * 4 + 1];
            float a2 = As[k][ty * 4 + 2], a3 = As[k][ty * 4 + 3];
            float b0 = Bs[k][tx * 4 + 0], b1 = Bs[k][tx * 4 + 1];
            float b2 = Bs[k][tx * 4 + 2], b3 = Bs[k][tx * 4 + 3];
            acc[0][0] += a0 * b0; acc[0][1] += a0 * b1; acc[0][2] += a0 * b2; acc[0][3] += a0 * b3;
            acc[1][0] += a1 * b0; acc[1][1] += a1 * b1; acc[1][2] += a1 * b2; acc[1][3] += a1 * b3;
            acc[2][0] += a2 * b0; acc[2][1] += a2 * b1; acc[2][2] += a2 * b2; acc[2][3] += a2 * b3;
            acc[3][0] += a3 * b0; acc[3][1] += a3 * b1; acc[3][2] += a3 * b2; acc[3][3] += a3 * b3;
        }
    }

    #pragma unroll
    for (int i = 0; i < 4; ++i) {
        const int m = m0 + ty * 4 + i;
        #pragma unroll
        for (int j = 0; j < 4; ++j) {
            const int n = n0 + tx * 4 + j;
            C[(size_t)m * kG4 + n] = __float2bfloat16(acc[i][j] + bih[n] + bhh[n]);
        }
    }
}

// ---------------------------------------------------------------------------
// Kernel 2: persistent LSTM recurrence. 256 WGs x 256 threads, 1 WG/CU.
// Sync protocol: wave 0 polls all 256 flags with RELAXED agent-scope loads
// (2 x 8-byte per lane), then ONE acquire fence per step per CU, then
// __syncthreads. Producer: one RELEASE flag store per step.
// No per-poll cache invalidation -> L2 stays warm.
// ---------------------------------------------------------------------------
__global__ __launch_bounds__(256, 1) void k_lstm(const float* __restrict__ Whh,
                                                 const __hip_bfloat16* __restrict__ xp,
                                                 float* __restrict__ hg,        // [2][kH]
                                                 uint32_t* __restrict__ flags,  // [kNB]
                                                 uint32_t* __restrict__ abortf,
                                                 __hip_bfloat16* __restrict__ hs)
{
    extern __shared__ char smem[];
    __hip_bfloat16* Wl   = (__hip_bfloat16*)smem;                     // [32][kWP] bf16
    float*          hl   = (float*)(smem + 32 * kWP * 2);             // [kH] fp32
    float*          gbuf = (float*)(smem + 32 * kWP * 2 + kH * 4);    // [4][8]
    float*          xbuf = gbuf + 32;                                 // [4][8]

    const int wg  = blockIdx.x;
    const int tid = threadIdx.x;
    const int w   = tid >> 6;   // wave id == gate id
    const int l   = tid & 63;
    const int hb  = wg * kHB;

    // ---- one-time: load + convert W_hh slice to LDS bf16 (padded rows) ----
    {
        const int lr = tid >> 3;             // LDS row 0..31
        const int g  = lr >> 3, j = lr & 7;  // gate, sub-index
        const int cb = (tid & 7) * 256;
        const float* src = Whh + (size_t)(g * kH + hb + j) * kH + cb;
        __hip_bfloat16* dst = Wl + (size_t)lr * kWP + cb;
        for (int c = 0; c < 256; c += 4) {
            float4 v = *(const float4*)(src + c);
            dst[c + 0] = __float2bfloat16(v.x);
            dst[c + 1] = __float2bfloat16(v.y);
            dst[c + 2] = __float2bfloat16(v.z);
            dst[c + 3] = __float2bfloat16(v.w);
        }
    }
    __syncthreads();

    float c_state = 0.0f;                                  // lanes tid<8 carry c
    const __hip_bfloat16* wrow = Wl + (size_t)(w * 8 + (l >> 3)) * kWP;
    const int kbase = (l & 7) * 8;
    uint32_t budget = 0;        // whole-kernel poll budget (wave 0 only)

    const unsigned long long* f64 = (const unsigned long long*)flags + (size_t)l * 2;

    for (int t = 0; t < kSEQ; ++t) {
        // ---- barrier: wave 0 waits until every WG published h_{t-1} ----
        int dead = 0;
        if (w == 0) {
            const uint32_t tgt = (uint32_t)t;
            for (;;) {
                unsigned long long a = __hip_atomic_load(f64,     __ATOMIC_RELAXED, __HIP_MEMORY_SCOPE_AGENT);
                unsigned long long b = __hip_atomic_load(f64 + 1, __ATOMIC_RELAXED, __HIP_MEMORY_SCOPE_AGENT);
                if ((uint32_t)a >= tgt && (uint32_t)(a >> 32) >= tgt &&
                    (uint32_t)b >= tgt && (uint32_t)(b >> 32) >= tgt) break;
                if ((++budget & 255) == 0) {
                    if (__hip_atomic_load(abortf, __ATOMIC_RELAXED,
                                          __HIP_MEMORY_SCOPE_AGENT) != 0u) { dead = 1; break; }
                    if (budget > (1u << 23)) {   // whole-kernel bound -> poison abort
                        __hip_atomic_store(abortf, 1u, __ATOMIC_RELAXED,
                                           __HIP_MEMORY_SCOPE_AGENT);
                        dead = 1; break;
                    }
                }
            }
            // One invalidate per step per CU; covers all 4 waves (1 WG/CU).
            __builtin_amdgcn_fence(__ATOMIC_ACQUIRE, "agent");
        }
        if (__syncthreads_or(dead)) return;   // uniform exit: never hang

        // ---- stage h_{t-1} (buffer t&1) into LDS; fetch this step's x_proj ----
        {
            const float* src = hg + (size_t)(t & 1) * kH + tid * 8;
            float4 a = *(const float4*)(src);
            float4 b = *(const float4*)(src + 4);
            float* d = hl + tid * 8;
            *(float4*)(d)     = a;
            *(float4*)(d + 4) = b;
            if (tid < 32)
                xbuf[tid] = __bfloat162float(xp[(size_t)t * kG4 + (tid >> 3) * kH + hb + (tid & 7)]);
        }
        __syncthreads();

        // ---- matvec: lane (j=l>>3, ksub=l&7); 32 iters x 8 MACs ----
        float acc = 0.f;
        #pragma unroll 8
        for (int it = 0; it < 32; ++it) {
            const int k = it * 64 + kbase;
            uint4 wv = *(const uint4*)(wrow + k);
            float4 h0 = *(const float4*)(hl + k);
            float4 h1 = *(const float4*)(hl + k + 4);
            acc += bflo(wv.x) * h0.x + bfhi(wv.x) * h0.y
                 + bflo(wv.y) * h0.z + bfhi(wv.y) * h0.w
                 + bflo(wv.z) * h1.x + bfhi(wv.z) * h1.y
                 + bflo(wv.w) * h1.z + bfhi(wv.w) * h1.w;
        }
        acc += __shfl_xor(acc, 1);
        acc += __shfl_xor(acc, 2);
        acc += __shfl_xor(acc, 4);
        if ((l & 7) == 0) gbuf[w * 8 + (l >> 3)] = acc;
        __syncthreads();

        // ---- gate nonlinearities + state update (8 lanes) ----
        if (tid < 8) {
            const int j = tid;
            const float gi = gbuf[0 * 8 + j] + xbuf[0 * 8 + j];
            const float gf = gbuf[1 * 8 + j] + xbuf[1 * 8 + j];
            const float gg = gbuf[2 * 8 + j] + xbuf[2 * 8 + j];
            const float go = gbuf[3 * 8 + j] + xbuf[3 * 8 + j];
            const float si = 1.f / (1.f + expf(-gi));
            const float sf = 1.f / (1.f + expf(-gf));
            const float tg = tanhf(gg);
            const float so = 1.f / (1.f + expf(-go));
            c_state = sf * c_state + si * tg;
            const float hv = so * tanhf(c_state);
            hg[(size_t)((t + 1) & 1) * kH + hb + j] = hv;          // plain store
            hs[(size_t)t * kH + hb + j] = __float2bfloat16(hv);
        }
        __syncthreads();   // drains vmcnt for all waves before publish
        if (tid == 0)
            __hip_atomic_store(&flags[wg], (uint32_t)(t + 1), __ATOMIC_RELEASE,
                               __HIP_MEMORY_SCOPE_AGENT);
    }
}

// ---------------------------------------------------------------------------
// Kernel 3: out[t] = sigmoid(hs[t] . W_lin + b_lin). One wave per t.
// ---------------------------------------------------------------------------
__global__ __launch_bounds__(256) void k_out(const __hip_bfloat16* __restrict__ hs,
                                             const float* __restrict__ wlin,
                                             const float* __restrict__ blin,
                                             float* __restrict__ out)
{
    const int w = threadIdx.x >> 6, l = threadIdx.x & 63;
    const int t = blockIdx.x * 4 + w;
    const __hip_bfloat16* row = hs + (size_t)t * kH;
    float acc = 0.f;
    #pragma unroll
    for (int i = 0; i < 4; ++i) {
        const int k = i * 512 + l * 8;
        uint4 hv = *(const uint4*)(row + k);
        float4 w0 = *(const float4*)(wlin + k);
        float4 w1 = *(const float4*)(wlin + k + 4);
        acc += bflo(hv.x) * w0.x + bfhi(hv.x) * w0.y
             + bflo(hv.y) * w0.z + bfhi(hv.y) * w0.w
             + bflo(hv.z) * w1.x + bfhi(hv.z) * w1.y
             + bflo(hv.w) * w1.z + bfhi(hv.w) * w1.w;
    }
    #pragma unroll
    for (int s = 32; s >= 1; s >>= 1) acc += __shfl_xor(acc, s);
    if (l == 0) out[t] = 1.f / (1.f + expf(-(acc + blin[0])));
}

// ---------------------------------------------------------------------------
extern "C" void kernel_launch(void* const* d_in, const int* in_sizes, int n_in,
                              void* d_out, int out_size, void* d_ws, size_t ws_size,
                              hipStream_t stream)
{
    const float* input_seq = (const float*)d_in[0];
    const float* W_ih      = (const float*)d_in[1];
    const float* W_hh      = (const float*)d_in[2];
    const float* b_ih      = (const float*)d_in[3];
    const float* b_hh      = (const float*)d_in[4];
    const float* W_lin     = (const float*)d_in[5];
    const float* b_lin     = (const float*)d_in[6];
    float* out = (float*)d_out;
    char*  ws  = (char*)d_ws;

    float*          hg    = (float*)(ws + OFF_HG);
    uint32_t*       flags = (uint32_t*)(ws + OFF_FLAGS);
    uint32_t*       abf   = (uint32_t*)(ws + OFF_ABORT);
    __hip_bfloat16* hs    = (__hip_bfloat16*)(ws + OFF_HS);
    __hip_bfloat16* xpb   = (__hip_bfloat16*)(ws + OFF_XP);

    // zero h double-buffer + flags + abort each call (harness does not re-poison)
    hipMemsetAsync(ws, 0, 65536, stream);

    k_xproj<<<dim3(128 * 128), dim3(256), 0, stream>>>(input_seq, W_ih, b_ih, b_hh, xpb);

    constexpr int kLds = 32 * kWP * 2 + kH * 4 + 64 * 4;   // 140544 B
    hipFuncSetAttribute((const void*)k_lstm, hipFuncAttributeMaxDynamicSharedMemorySize, kLds);

    // Preferred: cooperative launch -> driver guarantees all 256 WGs co-resident,
    // so the flag barrier is provably live. Fallback: plain launch (whole-kernel
    // bounded spin + sticky abort still prevents any hang).
    {
        const float* a0 = W_hh; const __hip_bfloat16* a1 = xpb; float* a2 = hg;
        uint32_t* a3 = flags; uint32_t* a4 = abf; __hip_bfloat16* a5 = hs;
        void* args[6] = { &a0, &a1, &a2, &a3, &a4, &a5 };
        hipError_t ce = hipLaunchCooperativeKernel((const void*)k_lstm, dim3(kNB), dim3(256),
                                                   args, (unsigned)kLds, stream);
        if (ce != hipSuccess) {
            k_lstm<<<dim3(kNB), dim3(256), kLds, stream>>>(W_hh, xpb, hg, flags, abf, hs);
        }
    }

    k_out<<<dim3(kSEQ / 4), dim3(256), 0, stream>>>(hs, W_lin, b_lin, out);
}

// Round 9
// 55082.166 us; speedup vs baseline: 3.4835x; 1.8366x over previous
//
#include <hip/hip_runtime.h>
#include <hip/hip_bf16.h>
#include <stdint.h>

constexpr int kSEQ = 8192;
constexpr int kIN  = 1024;
constexpr int kH   = 2048;
constexpr int kG4  = 4 * kH;   // 8192 gate rows
constexpr int kNB  = 256;      // persistent workgroups (1 per CU)
constexpr int kHB  = kH / kNB; // 8 h-values owned per WG
constexpr int kWP  = kH + 16;  // LDS row stride (intrinsic b128 cost dominates; pad kept)

// ---- workspace layout (bytes) ----
constexpr size_t OFF_HBUF  = 0;          // u64 hbuf[2][kH]  (32 KB) tagged h words
constexpr size_t OFF_ABORT = 32768;      // uint32 abort flag
constexpr size_t OFF_HS    = 65536;      // bf16 hs[kSEQ][kH]   (32 MB)
constexpr size_t OFF_XP    = OFF_HS + (size_t)kSEQ * kH * 2; // bf16 xp[kSEQ][kG4] (128 MB)

__device__ __forceinline__ float bflo(uint32_t v) { return __uint_as_float(v << 16); }
__device__ __forceinline__ float bfhi(uint32_t v) { return __uint_as_float(v & 0xffff0000u); }

// ---------------------------------------------------------------------------
// Kernel 1: x_proj[m][n] = sum_k input[m][k] * W_ih[n][k] + b_ih[n] + b_hh[n]
// fp32 LDS-tiled GEMM, 64x64 tile, BK=16, 256 threads, 4x4 per thread.
// ---------------------------------------------------------------------------
__global__ __launch_bounds__(256) void k_xproj(const float* __restrict__ A,
                                               const float* __restrict__ B,
                                               const float* __restrict__ bih,
                                               const float* __restrict__ bhh,
                                               __hip_bfloat16* __restrict__ C)
{
    __shared__ float As[16][65];
    __shared__ float Bs[16][65];

    const int bx = blockIdx.x & 127;   // n tile
    const int by = blockIdx.x >> 7;    // m tile
    const int tid = threadIdx.x;
    const int r  = tid >> 2;           // 0..63 row within tile
    const int kq = (tid & 3) << 2;     // 0,4,8,12
    const int tx = tid & 15;
    const int ty = tid >> 4;
    const int m0 = by * 64, n0 = bx * 64;

    float acc[4][4] = {};

    for (int k0 = 0; k0 < kIN; k0 += 16) {
        float4 av = *(const float4*)&A[(size_t)(m0 + r) * kIN + k0 + kq];
        float4 bv = *(const float4*)&B[(size_t)(n0 + r) * kIN + k0 + kq];
        __syncthreads();   // protect previous iteration's reads
        As[kq + 0][r] = av.x; As[kq + 1][r] = av.y; As[kq + 2][r] = av.z; As[kq + 3][r] = av.w;
        Bs[kq + 0][r] = bv.x; Bs[kq + 1][r] = bv.y; Bs[kq + 2][r] = bv.z; Bs[kq + 3][r] = bv.w;
        __syncthreads();
        #pragma unroll
        for (int k = 0; k < 16; ++k) {
            float a0 = As[k][ty * 4 + 0], a1 = As[k][ty * 4 + 1];
            float a2 = As[k][ty * 4 + 2], a3 = As[k][ty * 4 + 3];
            float b0 = Bs[k][tx * 4 + 0], b1 = Bs[k][tx * 4 + 1];
            float b2 = Bs[k][tx * 4 + 2], b3 = Bs[k][tx * 4 + 3];
            acc[0][0] += a0 * b0; acc[0][1] += a0 * b1; acc[0][2] += a0 * b2; acc[0][3] += a0 * b3;
            acc[1][0] += a1 * b0; acc[1][1] += a1 * b1; acc[1][2] += a1 * b2; acc[1][3] += a1 * b3;
            acc[2][0] += a2 * b0; acc[2][1] += a2 * b1; acc[2][2] += a2 * b2; acc[2][3] += a2 * b3;
            acc[3][0] += a3 * b0; acc[3][1] += a3 * b1; acc[3][2] += a3 * b2; acc[3][3] += a3 * b3;
        }
    }

    #pragma unroll
    for (int i = 0; i < 4; ++i) {
        const int m = m0 + ty * 4 + i;
        #pragma unroll
        for (int j = 0; j < 4; ++j) {
            const int n = n0 + tx * 4 + j;
            C[(size_t)m * kG4 + n] = __float2bfloat16(acc[i][j] + bih[n] + bhh[n]);
        }
    }
}

// ---------------------------------------------------------------------------
// Kernel 2: persistent LSTM recurrence. 256 WGs x 256 threads, 1 WG/CU.
// DATA-CARRYING SYNC: each h value is published as one u64 word
//   (f32_bits(h) << 32) | (t+1)
// into hbuf[t&1][gidx] with a relaxed agent-scope atomic store. Consumers
// poll the words directly (relaxed atomic u64 loads): tag match => h valid
// (single-word atomicity). No flags, no release writeback, no acquire
// invalidate, no separate h read. Double-buffer + tag ordering is race-free:
// slot overwrite is gated on all WGs publishing the NEXT step, which
// certifies consumption of the current slot.
// ---------------------------------------------------------------------------
__global__ __launch_bounds__(256, 1) void k_lstm(const float* __restrict__ Whh,
                                                 const __hip_bfloat16* __restrict__ xp,
                                                 unsigned long long* __restrict__ hbuf, // [2][kH]
                                                 uint32_t* __restrict__ abortf,
                                                 __hip_bfloat16* __restrict__ hs)
{
    extern __shared__ char smem[];
    __hip_bfloat16* Wl   = (__hip_bfloat16*)smem;                     // [32][kWP] bf16
    float*          hl   = (float*)(smem + 32 * kWP * 2);             // [kH] fp32
    float*          gbuf = (float*)(smem + 32 * kWP * 2 + kH * 4);    // [4][8]
    float*          xbuf = gbuf + 32;                                 // [4][8]

    const int wg  = blockIdx.x;
    const int tid = threadIdx.x;
    const int w   = tid >> 6;   // wave id == gate id
    const int l   = tid & 63;
    const int hb  = wg * kHB;

    // ---- one-time: load + convert W_hh slice to LDS bf16 ----
    {
        const int lr = tid >> 3;             // LDS row 0..31
        const int g  = lr >> 3, j = lr & 7;  // gate, sub-index
        const int cb = (tid & 7) * 256;
        const float* src = Whh + (size_t)(g * kH + hb + j) * kH + cb;
        __hip_bfloat16* dst = Wl + (size_t)lr * kWP + cb;
        for (int c = 0; c < 256; c += 4) {
            float4 v = *(const float4*)(src + c);
            dst[c + 0] = __float2bfloat16(v.x);
            dst[c + 1] = __float2bfloat16(v.y);
            dst[c + 2] = __float2bfloat16(v.z);
            dst[c + 3] = __float2bfloat16(v.w);
        }
    }
    __syncthreads();

    float c_state = 0.0f;                                  // lanes tid<8 carry c
    const __hip_bfloat16* wrow = Wl + (size_t)(w * 8 + (l >> 3)) * kWP;
    const int kbase = (l & 7) * 8;
    uint32_t budget = 0;        // whole-kernel poll budget (liveness bound)

    for (int t = 0; t < kSEQ; ++t) {
        // ---- issue this step's x_proj load early; it retires under polling ----
        float xv = 0.f;
        if (tid < 32)
            xv = __bfloat162float(xp[(size_t)t * kG4 + (tid >> 3) * kH + hb + (tid & 7)]);

        // ---- gather h_{t-1}: thread tid owns WG tid's 8 words ----
        int dead = 0;
        if (t == 0) {
            float* d = hl + tid * 8;
            #pragma unroll
            for (int j = 0; j < 8; ++j) d[j] = 0.f;
        } else {
            const unsigned long long* src = hbuf + (size_t)((t - 1) & 1) * kH + tid * 8;
            const uint32_t tag = (uint32_t)t;   // publication tag of h_{t-1}
            float* d = hl + tid * 8;
            #pragma unroll 1
            for (int j = 0; j < 8 && !dead; ++j) {
                unsigned long long v;
                for (;;) {
                    v = __hip_atomic_load(src + j, __ATOMIC_RELAXED, __HIP_MEMORY_SCOPE_AGENT);
                    if ((uint32_t)v == tag) break;
                    if ((++budget & 1023) == 0) {
                        if (__hip_atomic_load(abortf, __ATOMIC_RELAXED,
                                              __HIP_MEMORY_SCOPE_AGENT) != 0u) { dead = 1; break; }
                        if (budget > (1u << 22)) {   // whole-kernel bound -> poison abort
                            __hip_atomic_store(abortf, 1u, __ATOMIC_RELAXED,
                                               __HIP_MEMORY_SCOPE_AGENT);
                            dead = 1; break;
                        }
                    }
                }
                d[j] = __uint_as_float((uint32_t)(v >> 32));
            }
        }
        if (tid < 32) xbuf[tid] = xv;
        if (__syncthreads_or(dead)) return;   // uniform exit: never hang

        // ---- matvec: lane (j=l>>3, ksub=l&7); 32 iters x 8 MACs ----
        float acc = 0.f;
        #pragma unroll 8
        for (int it = 0; it < 32; ++it) {
            const int k = it * 64 + kbase;
            uint4 wv = *(const uint4*)(wrow + k);
            float4 h0 = *(const float4*)(hl + k);
            float4 h1 = *(const float4*)(hl + k + 4);
            acc += bflo(wv.x) * h0.x + bfhi(wv.x) * h0.y
                 + bflo(wv.y) * h0.z + bfhi(wv.y) * h0.w
                 + bflo(wv.z) * h1.x + bfhi(wv.z) * h1.y
                 + bflo(wv.w) * h1.z + bfhi(wv.w) * h1.w;
        }
        acc += __shfl_xor(acc, 1);
        acc += __shfl_xor(acc, 2);
        acc += __shfl_xor(acc, 4);
        if ((l & 7) == 0) gbuf[w * 8 + (l >> 3)] = acc;
        __syncthreads();

        // ---- gate nonlinearities + state update + tagged publish (8 lanes) ----
        if (tid < 8) {
            const int j = tid;
            const float gi = gbuf[0 * 8 + j] + xbuf[0 * 8 + j];
            const float gf = gbuf[1 * 8 + j] + xbuf[1 * 8 + j];
            const float gg = gbuf[2 * 8 + j] + xbuf[2 * 8 + j];
            const float go = gbuf[3 * 8 + j] + xbuf[3 * 8 + j];
            const float si = 1.f / (1.f + expf(-gi));
            const float sf = 1.f / (1.f + expf(-gf));
            const float tg = tanhf(gg);
            const float so = 1.f / (1.f + expf(-go));
            c_state = sf * c_state + si * tg;
            const float hv = so * tanhf(c_state);
            hs[(size_t)t * kH + hb + j] = __float2bfloat16(hv);
            const unsigned long long pv =
                ((unsigned long long)__float_as_uint(hv) << 32) | (uint32_t)(t + 1);
            __hip_atomic_store(hbuf + (size_t)(t & 1) * kH + hb + j, pv,
                               __ATOMIC_RELAXED, __HIP_MEMORY_SCOPE_AGENT);
        }
        // no trailing barrier: next iteration's poll self-synchronizes via tags
    }
}

// ---------------------------------------------------------------------------
// Kernel 3: out[t] = sigmoid(hs[t] . W_lin + b_lin). One wave per t.
// ---------------------------------------------------------------------------
__global__ __launch_bounds__(256) void k_out(const __hip_bfloat16* __restrict__ hs,
                                             const float* __restrict__ wlin,
                                             const float* __restrict__ blin,
                                             float* __restrict__ out)
{
    const int w = threadIdx.x >> 6, l = threadIdx.x & 63;
    const int t = blockIdx.x * 4 + w;
    const __hip_bfloat16* row = hs + (size_t)t * kH;
    float acc = 0.f;
    #pragma unroll
    for (int i = 0; i < 4; ++i) {
        const int k = i * 512 + l * 8;
        uint4 hv = *(const uint4*)(row + k);
        float4 w0 = *(const float4*)(wlin + k);
        float4 w1 = *(const float4*)(wlin + k + 4);
        acc += bflo(hv.x) * w0.x + bfhi(hv.x) * w0.y
             + bflo(hv.y) * w0.z + bfhi(hv.y) * w0.w
             + bflo(hv.z) * w1.x + bfhi(hv.z) * w1.y
             + bflo(hv.w) * w1.z + bfhi(hv.w) * w1.w;
    }
    #pragma unroll
    for (int s = 32; s >= 1; s >>= 1) acc += __shfl_xor(acc, s);
    if (l == 0) out[t] = 1.f / (1.f + expf(-(acc + blin[0])));
}

// ---------------------------------------------------------------------------
extern "C" void kernel_launch(void* const* d_in, const int* in_sizes, int n_in,
                              void* d_out, int out_size, void* d_ws, size_t ws_size,
                              hipStream_t stream)
{
    const float* input_seq = (const float*)d_in[0];
    const float* W_ih      = (const float*)d_in[1];
    const float* W_hh      = (const float*)d_in[2];
    const float* b_ih      = (const float*)d_in[3];
    const float* b_hh      = (const float*)d_in[4];
    const float* W_lin     = (const float*)d_in[5];
    const float* b_lin     = (const float*)d_in[6];
    float* out = (float*)d_out;
    char*  ws  = (char*)d_ws;

    unsigned long long* hbuf = (unsigned long long*)(ws + OFF_HBUF);
    uint32_t*           abf  = (uint32_t*)(ws + OFF_ABORT);
    __hip_bfloat16*     hs   = (__hip_bfloat16*)(ws + OFF_HS);
    __hip_bfloat16*     xpb  = (__hip_bfloat16*)(ws + OFF_XP);

    // zero hbuf tags + abort each call (harness does not re-poison between replays)
    hipMemsetAsync(ws, 0, 65536, stream);

    k_xproj<<<dim3(128 * 128), dim3(256), 0, stream>>>(input_seq, W_ih, b_ih, b_hh, xpb);

    constexpr int kLds = 32 * kWP * 2 + kH * 4 + 64 * 4;   // 140544 B
    hipFuncSetAttribute((const void*)k_lstm, hipFuncAttributeMaxDynamicSharedMemorySize, kLds);

    // Preferred: cooperative launch -> driver guarantees all 256 WGs co-resident,
    // so the tag-poll is provably live. Fallback: plain launch (whole-kernel
    // bounded spin + sticky abort still prevents any hang).
    {
        const float* a0 = W_hh; const __hip_bfloat16* a1 = xpb;
        unsigned long long* a2 = hbuf; uint32_t* a3 = abf; __hip_bfloat16* a4 = hs;
        void* args[5] = { &a0, &a1, &a2, &a3, &a4 };
        hipError_t ce = hipLaunchCooperativeKernel((const void*)k_lstm, dim3(kNB), dim3(256),
                                                   args, (unsigned)kLds, stream);
        if (ce != hipSuccess) {
            k_lstm<<<dim3(kNB), dim3(256), kLds, stream>>>(W_hh, xpb, hbuf, abf, hs);
        }
    }

    k_out<<<dim3(kSEQ / 4), dim3(256), 0, stream>>>(hs, W_lin, b_lin, out);
}